// Round 5
// baseline (713.855 us; speedup 1.0000x reference)
//
#include <hip/hip_runtime.h>
#include <math.h>

// ---------------------------------------------------------------------------
// B=256 images, N=256 tokens/image. L1: Cu=12,d=16(dh=4),r=16 -> 64ch.
// L2: Cu=64,d=32(dh=8),r=32 -> 128ch. shuffle(L1) o unshuffle(L2) == identity.
// R5: de-spill attn kernels (R4: VGPR=256, 100MB scratch traffic).
//   - neighbor phases per-head (static indices, small live set)
//   - attn1 phase B 2-token blocking (32 acc regs)
// Selection-critical path (q/k/t2) stays exact fp32.
// ---------------------------------------------------------------------------

typedef float floatx4 __attribute__((ext_vector_type(4)));
typedef __bf16 bf16x8 __attribute__((ext_vector_type(8)));

// ---- workspace layout (float offsets), peak 50.3 MB ----
static constexpr size_t OQ1 = 0;          // [B,256,16] 1048576
static constexpr size_t OK1 = 1048576;
static constexpr size_t OV1 = 2097152;
static constexpr size_t OL1 = 3145728;    // ..4194304
static constexpr size_t OT2 = 4194304;    // [B,256,64] fp32 ..8388608
static constexpr size_t OQ2 = 0;          // [B,256,32] ..2097152 (q1/k1 dead)
static constexpr size_t OK2 = 2097152;    // ..4194304 (v1/loc1 dead)
static constexpr size_t OV2 = 8388608;    // ..10485760
static constexpr size_t OL2 = 10485760;   // ..12582912
static constexpr size_t OH  = 4194304;    // h bf16 [256,32768] (t2 dead)
static constexpr size_t OPART = 8388608;  // [16][256][1024] fp32 ..12582912

__device__ inline bf16x8 pack8(const float* f) {
  bf16x8 v;
#pragma unroll
  for (int i = 0; i < 8; ++i) v[i] = (__bf16)f[i];
  return v;
}

// ---------------- K1: pixel_unshuffle + q/k/v/local projections, layer 1 ----
__global__ __launch_bounds__(256) void k1_qkv1(
    const float* __restrict__ x, const float* __restrict__ w1q,
    const float* __restrict__ w1k, const float* __restrict__ w1v,
    const float* __restrict__ w1c, const float* __restrict__ b1c,
    float* __restrict__ q1, float* __restrict__ k1,
    float* __restrict__ v1, float* __restrict__ loc1)
{
  const int tid = threadIdx.x;
  const int slot = tid >> 6;
  const int lane = tid & 63;
  const int tok = blockIdx.x * 4 + slot;   // b*256+n
  const int b = tok >> 8, n = tok & 255;
  const int i = n >> 4, j = n & 15;
  __shared__ float ts[4][12];
  if (lane < 12) {
    const int c0 = lane >> 2, si = (lane >> 1) & 1, sj = lane & 1;
    ts[slot][lane] = x[((size_t)(b * 3 + c0) * 32 + 2 * i + si) * 32 + 2 * j + sj];
  }
  __syncthreads();
  const int mat = lane >> 4, col = lane & 15;
  const float* W = (mat == 0) ? w1q : (mat == 1) ? w1k : (mat == 2) ? w1v : w1c;
  float acc = 0.f;
#pragma unroll
  for (int c = 0; c < 12; ++c) acc += ts[slot][c] * W[c * 16 + col];
  const size_t o = (size_t)tok * 16 + col;
  if (mat == 0) q1[o] = acc;
  else if (mat == 1) k1[o] = acc;
  else if (mat == 2) v1[o] = acc;
  else loc1[o] = fmaxf(acc + b1c[col], 0.f);
}

// ---------------- attn1 + out-proj1 fused: 1 block/image -------------------
// Phase A: per-thread top-9 scan over LDS K (verified R3/R4).
// Neighbor phases per-head: small static live set, no spills.
// Phase B: t2 = [loc1|agg] @ W1o + b1o exact fp32, 2x2-token blocking.
__global__ __launch_bounds__(256) void attn1_out(
    const float* __restrict__ q, const float* __restrict__ k,
    const float* __restrict__ v, const float* __restrict__ loc1,
    const float* __restrict__ w1o, const float* __restrict__ b1o,
    float* __restrict__ t2)
{
  constexpr int D = 16, NH = 4;
  const int b = blockIdx.x;
  const int t = threadIdx.x;
  __shared__ float ks[256 * D];      // 16 KB
  __shared__ float catS[256 * 36];   // 36.9 KB
  __shared__ float wS[32 * 64];      // 8 KB
  const size_t base = (size_t)b * (256 * D);
  for (int idx = t * 4; idx < 256 * D; idx += 1024)
    *(float4*)&ks[idx] = *(const float4*)&k[base + idx];
  for (int idx = t * 4; idx < 2048; idx += 1024)
    *(float4*)&wS[idx] = *(const float4*)&w1o[idx];
  float qr[D];
  {
    const float4* qrow = (const float4*)&q[base + (size_t)t * D];
#pragma unroll
    for (int c4 = 0; c4 < D / 4; ++c4) {
      const float4 qv = qrow[c4];
      qr[4 * c4 + 0] = qv.x; qr[4 * c4 + 1] = qv.y;
      qr[4 * c4 + 2] = qv.z; qr[4 * c4 + 3] = qv.w;
    }
  }
  __syncthreads();

  float topv[9];
  int topi[9];
#pragma unroll
  for (int r = 0; r < 9; ++r) { topv[r] = -__builtin_inff(); topi[r] = 0; }

#pragma unroll 2
  for (int m = 0; m < 256; ++m) {
    const float4* kr = (const float4*)&ks[m * D];
    float p0 = 0.f, p1 = 0.f, p2 = 0.f, p3 = 0.f;
    {
      float4 kv;
      kv = kr[0];
      p0 += qr[0] * kv.x + qr[1] * kv.y + qr[2] * kv.z + qr[3] * kv.w;
      kv = kr[1];
      p1 += qr[4] * kv.x + qr[5] * kv.y + qr[6] * kv.z + qr[7] * kv.w;
      kv = kr[2];
      p2 += qr[8] * kv.x + qr[9] * kv.y + qr[10] * kv.z + qr[11] * kv.w;
      kv = kr[3];
      p3 += qr[12] * kv.x + qr[13] * kv.y + qr[14] * kv.z + qr[15] * kv.w;
    }
    const float s = (p0 + p1) + (p2 + p3);
    bool ci = s > topv[8];
#pragma unroll
    for (int i = 8; i >= 1; --i) {
      const bool cim1 = s > topv[i - 1];
      topv[i] = ci ? (cim1 ? topv[i - 1] : s) : topv[i];
      topi[i] = ci ? (cim1 ? topi[i - 1] : m) : topi[i];
      ci = cim1;
    }
    topv[0] = ci ? s : topv[0];
    topi[0] = ci ? m : topi[0];
  }

  // per-head neighbor logits -> softmax -> V aggregation (static indices)
  float outr[D];
#pragma unroll
  for (int hh = 0; hh < NH; ++hh) {
    float lg9[9];
#pragma unroll
    for (int kk = 0; kk < 9; ++kk) {
      const float4 ka = *(const float4*)&k[base + (size_t)topi[kk] * D + hh * 4];
      lg9[kk] = (qr[hh * 4 + 0] * ka.x + qr[hh * 4 + 1] * ka.y +
                 qr[hh * 4 + 2] * ka.z + qr[hh * 4 + 3] * ka.w) * 0.5f;
    }
    float mx = lg9[0];
#pragma unroll
    for (int kk = 1; kk < 9; ++kk) mx = fmaxf(mx, lg9[kk]);
    float sum = 0.f;
#pragma unroll
    for (int kk = 0; kk < 9; ++kk) { lg9[kk] = __expf(lg9[kk] - mx); sum += lg9[kk]; }
    const float inv = 1.f / sum;
    float ox = 0.f, oy = 0.f, oz = 0.f, ow = 0.f;
#pragma unroll
    for (int kk = 0; kk < 9; ++kk) {
      const float4 va = *(const float4*)&v[base + (size_t)topi[kk] * D + hh * 4];
      const float w = lg9[kk] * inv;
      ox += w * va.x; oy += w * va.y; oz += w * va.z; ow += w * va.w;
    }
    outr[hh * 4 + 0] = ox; outr[hh * 4 + 1] = oy;
    outr[hh * 4 + 2] = oz; outr[hh * 4 + 3] = ow;
  }

  // phase B: stage cat rows, then fp32 out-projection (exact — feeds top-k 2)
#pragma unroll
  for (int c4 = 0; c4 < 4; ++c4) {
    *(float4*)&catS[t * 36 + c4 * 4] =
        *(const float4*)&loc1[(size_t)(b * 256 + t) * 16 + c4 * 4];
    *(float4*)&catS[t * 36 + 16 + c4 * 4] =
        make_float4(outr[4 * c4], outr[4 * c4 + 1], outr[4 * c4 + 2], outr[4 * c4 + 3]);
  }
  __syncthreads();
  const int tq = t >> 2, quarter = t & 3;
  float4 bia[4];
#pragma unroll
  for (int o4 = 0; o4 < 4; ++o4)
    bia[o4] = *(const float4*)&b1o[quarter * 16 + o4 * 4];
#pragma unroll
  for (int g = 0; g < 2; ++g) {       // 2 groups x 2 tokens: 32 acc regs live
    float acc2[2][16];
#pragma unroll
    for (int u = 0; u < 2; ++u)
#pragma unroll
      for (int o4 = 0; o4 < 4; ++o4) {
        acc2[u][o4 * 4 + 0] = bia[o4].x; acc2[u][o4 * 4 + 1] = bia[o4].y;
        acc2[u][o4 * 4 + 2] = bia[o4].z; acc2[u][o4 * 4 + 3] = bia[o4].w;
      }
#pragma unroll
    for (int c4 = 0; c4 < 8; ++c4) {
      float4 cat4[2];
#pragma unroll
      for (int u = 0; u < 2; ++u)
        cat4[u] = *(const float4*)&catS[((g * 2 + u) * 64 + tq) * 36 + c4 * 4];
#pragma unroll
      for (int o4 = 0; o4 < 4; ++o4) {
        float4 w4[4];
#pragma unroll
        for (int i = 0; i < 4; ++i)
          w4[i] = *(const float4*)&wS[(c4 * 4 + i) * 64 + quarter * 16 + o4 * 4];
#pragma unroll
        for (int u = 0; u < 2; ++u) {
          acc2[u][o4*4+0] += cat4[u].x*w4[0].x + cat4[u].y*w4[1].x + cat4[u].z*w4[2].x + cat4[u].w*w4[3].x;
          acc2[u][o4*4+1] += cat4[u].x*w4[0].y + cat4[u].y*w4[1].y + cat4[u].z*w4[2].y + cat4[u].w*w4[3].y;
          acc2[u][o4*4+2] += cat4[u].x*w4[0].z + cat4[u].y*w4[1].z + cat4[u].z*w4[2].z + cat4[u].w*w4[3].z;
          acc2[u][o4*4+3] += cat4[u].x*w4[0].w + cat4[u].y*w4[1].w + cat4[u].z*w4[2].w + cat4[u].w*w4[3].w;
        }
      }
    }
#pragma unroll
    for (int u = 0; u < 2; ++u) {
      float* dst = t2 + (size_t)(b * 256 + (g * 2 + u) * 64 + tq) * 64 + quarter * 16;
#pragma unroll
      for (int o4 = 0; o4 < 4; ++o4)
        *(float4*)&dst[o4 * 4] = make_float4(acc2[u][o4*4], acc2[u][o4*4+1],
                                             acc2[u][o4*4+2], acc2[u][o4*4+3]);
    }
  }
}

// ---------------- K4: layer-2 q/k/v/local projections (exact fp32) ---------
__global__ __launch_bounds__(256) void k4_qkv2(
    const float* __restrict__ t2, const float* __restrict__ w2q,
    const float* __restrict__ w2k, const float* __restrict__ w2v,
    const float* __restrict__ w2c, const float* __restrict__ b2c,
    float* __restrict__ q2, float* __restrict__ k2,
    float* __restrict__ v2, float* __restrict__ loc2)
{
  const int b = blockIdx.x;
  const int tid = threadIdx.x;
  __shared__ float t2S[256 * 68];   // 69.6 KB
  __shared__ float wS[64 * 144];    // 36.9 KB  [c][mat*36 + col]
  __shared__ float bS[32];
  for (int idx = tid * 4; idx < 16384; idx += 1024) {
    const float4 vv = *(const float4*)&t2[(size_t)b * 16384 + idx];
    *(float4*)&t2S[(idx >> 6) * 68 + (idx & 63)] = vv;
  }
  for (int idx = tid * 4; idx < 2048; idx += 1024) {
    const int c = idx >> 5, col = idx & 31;
    *(float4*)&wS[c * 144 + 0 * 36 + col] = *(const float4*)&w2q[idx];
    *(float4*)&wS[c * 144 + 1 * 36 + col] = *(const float4*)&w2k[idx];
    *(float4*)&wS[c * 144 + 2 * 36 + col] = *(const float4*)&w2v[idx];
    *(float4*)&wS[c * 144 + 3 * 36 + col] = *(const float4*)&w2c[idx];
  }
  if (tid < 32) bS[tid] = b2c[tid];
  __syncthreads();
  const int tq = tid >> 2, quarter = tid & 3;   // quarter == which matrix
  float* dst = (quarter == 0) ? q2 : (quarter == 1) ? k2 : (quarter == 2) ? v2 : loc2;
#pragma unroll
  for (int ohalf = 0; ohalf < 2; ++ohalf) {
    float acc[4][16];
#pragma unroll
    for (int tt = 0; tt < 4; ++tt)
#pragma unroll
      for (int e = 0; e < 16; ++e) acc[tt][e] = 0.f;
#pragma unroll 4
    for (int c4 = 0; c4 < 16; ++c4) {
      float4 cat4[4];
#pragma unroll
      for (int tt = 0; tt < 4; ++tt)
        cat4[tt] = *(const float4*)&t2S[(tt * 64 + tq) * 68 + c4 * 4];
#pragma unroll
      for (int o4 = 0; o4 < 4; ++o4) {
        float4 w4[4];
#pragma unroll
        for (int i = 0; i < 4; ++i)
          w4[i] = *(const float4*)&wS[(c4 * 4 + i) * 144 + quarter * 36 + ohalf * 16 + o4 * 4];
#pragma unroll
        for (int tt = 0; tt < 4; ++tt) {
          acc[tt][o4*4+0] += cat4[tt].x*w4[0].x + cat4[tt].y*w4[1].x + cat4[tt].z*w4[2].x + cat4[tt].w*w4[3].x;
          acc[tt][o4*4+1] += cat4[tt].x*w4[0].y + cat4[tt].y*w4[1].y + cat4[tt].z*w4[2].y + cat4[tt].w*w4[3].y;
          acc[tt][o4*4+2] += cat4[tt].x*w4[0].z + cat4[tt].y*w4[1].z + cat4[tt].z*w4[2].z + cat4[tt].w*w4[3].z;
          acc[tt][o4*4+3] += cat4[tt].x*w4[0].w + cat4[tt].y*w4[1].w + cat4[tt].z*w4[2].w + cat4[tt].w*w4[3].w;
        }
      }
    }
#pragma unroll
    for (int tt = 0; tt < 4; ++tt) {
#pragma unroll
      for (int e = 0; e < 16; ++e) {
        float vv = acc[tt][e];
        if (quarter == 3) vv = fmaxf(vv + bS[ohalf * 16 + e], 0.f);
        acc[tt][e] = vv;
      }
      float* drow = dst + (size_t)(b * 256 + tt * 64 + tq) * 32 + ohalf * 16;
#pragma unroll
      for (int o4 = 0; o4 < 4; ++o4)
        *(float4*)&drow[o4 * 4] = make_float4(acc[tt][o4*4], acc[tt][o4*4+1],
                                              acc[tt][o4*4+2], acc[tt][o4*4+3]);
    }
  }
}

// ---------------- attn2 + out-proj2 + pixel-shuffle fused ------------------
__global__ __launch_bounds__(256) void attn2_out(
    const float* __restrict__ q, const float* __restrict__ k,
    const float* __restrict__ v, const float* __restrict__ loc2,
    const float* __restrict__ w2o, const float* __restrict__ b2o,
    __bf16* __restrict__ h)
{
  constexpr int D = 32, NH = 4;
  const int b = blockIdx.x;
  const int t = threadIdx.x;
  __shared__ float ks[256 * D];          // 32 KB
  __shared__ __bf16 catB[256 * 72];      // 36.9 KB
  __shared__ __bf16 wB[128 * 72];        // 18.4 KB  [n][k]
  const size_t base = (size_t)b * (256 * D);
  for (int idx = t * 4; idx < 256 * D; idx += 1024)
    *(float4*)&ks[idx] = *(const float4*)&k[base + idx];
  {  // stage W2o transposed to bf16 [n][k]
    const int n = t >> 1, khalf = t & 1;
    float wv[32];
#pragma unroll
    for (int j = 0; j < 32; ++j) wv[j] = w2o[(size_t)(khalf * 32 + j) * 128 + n];
#pragma unroll
    for (int j8 = 0; j8 < 4; ++j8)
      *(bf16x8*)&wB[n * 72 + khalf * 32 + j8 * 8] = pack8(&wv[j8 * 8]);
  }
  float qr[D];
  {
    const float4* qrow = (const float4*)&q[base + (size_t)t * D];
#pragma unroll
    for (int c4 = 0; c4 < D / 4; ++c4) {
      const float4 qv = qrow[c4];
      qr[4 * c4 + 0] = qv.x; qr[4 * c4 + 1] = qv.y;
      qr[4 * c4 + 2] = qv.z; qr[4 * c4 + 3] = qv.w;
    }
  }
  __syncthreads();

  float topv[9];
  int topi[9];
#pragma unroll
  for (int r = 0; r < 9; ++r) { topv[r] = -__builtin_inff(); topi[r] = 0; }

#pragma unroll 2
  for (int m = 0; m < 256; ++m) {
    const float4* kr = (const float4*)&ks[m * D];
    float p0 = 0.f, p1 = 0.f, p2 = 0.f, p3 = 0.f;
#pragma unroll
    for (int c4 = 0; c4 < 8; c4 += 4) {
      float4 kv;
      kv = kr[c4 + 0];
      p0 += qr[4*c4+0]*kv.x + qr[4*c4+1]*kv.y + qr[4*c4+2]*kv.z + qr[4*c4+3]*kv.w;
      kv = kr[c4 + 1];
      p1 += qr[4*c4+4]*kv.x + qr[4*c4+5]*kv.y + qr[4*c4+6]*kv.z + qr[4*c4+7]*kv.w;
      kv = kr[c4 + 2];
      p2 += qr[4*c4+8]*kv.x + qr[4*c4+9]*kv.y + qr[4*c4+10]*kv.z + qr[4*c4+11]*kv.w;
      kv = kr[c4 + 3];
      p3 += qr[4*c4+12]*kv.x + qr[4*c4+13]*kv.y + qr[4*c4+14]*kv.z + qr[4*c4+15]*kv.w;
    }
    const float s = (p0 + p1) + (p2 + p3);
    bool ci = s > topv[8];
#pragma unroll
    for (int i = 8; i >= 1; --i) {
      const bool cim1 = s > topv[i - 1];
      topv[i] = ci ? (cim1 ? topv[i - 1] : s) : topv[i];
      topi[i] = ci ? (cim1 ? topi[i - 1] : m) : topi[i];
      ci = cim1;
    }
    topv[0] = ci ? s : topv[0];
    topi[0] = ci ? m : topi[0];
  }

  // per-head neighbor logits -> softmax -> V aggregation (static indices)
  float outr[D];
#pragma unroll
  for (int hh = 0; hh < NH; ++hh) {
    float lg9[9];
#pragma unroll
    for (int kk = 0; kk < 9; ++kk) {
      const float4* kr = (const float4*)&k[base + (size_t)topi[kk] * D + hh * 8];
      const float4 ka = kr[0], kb = kr[1];
      lg9[kk] = (qr[hh*8+0]*ka.x + qr[hh*8+1]*ka.y + qr[hh*8+2]*ka.z + qr[hh*8+3]*ka.w +
                 qr[hh*8+4]*kb.x + qr[hh*8+5]*kb.y + qr[hh*8+6]*kb.z + qr[hh*8+7]*kb.w)
                * 0.35355339059327373f;  // 1/sqrt(8)
    }
    float mx = lg9[0];
#pragma unroll
    for (int kk = 1; kk < 9; ++kk) mx = fmaxf(mx, lg9[kk]);
    float sum = 0.f;
#pragma unroll
    for (int kk = 0; kk < 9; ++kk) { lg9[kk] = __expf(lg9[kk] - mx); sum += lg9[kk]; }
    const float inv = 1.f / sum;
    float4 oa = make_float4(0.f, 0.f, 0.f, 0.f);
    float4 ob = make_float4(0.f, 0.f, 0.f, 0.f);
#pragma unroll
    for (int kk = 0; kk < 9; ++kk) {
      const float4* vr = (const float4*)&v[base + (size_t)topi[kk] * D + hh * 8];
      const float4 va = vr[0], vb = vr[1];
      const float w = lg9[kk] * inv;
      oa.x += w * va.x; oa.y += w * va.y; oa.z += w * va.z; oa.w += w * va.w;
      ob.x += w * vb.x; ob.y += w * vb.y; ob.z += w * vb.z; ob.w += w * vb.w;
    }
    outr[hh*8+0] = oa.x; outr[hh*8+1] = oa.y; outr[hh*8+2] = oa.z; outr[hh*8+3] = oa.w;
    outr[hh*8+4] = ob.x; outr[hh*8+5] = ob.y; outr[hh*8+6] = ob.z; outr[hh*8+7] = ob.w;
  }

  // phase B: write cat row (loc2|agg) as bf16, then MFMA out-projection
  {
    float lv[32];
#pragma unroll
    for (int c4 = 0; c4 < 8; ++c4) {
      const float4 x4 = *(const float4*)&loc2[(size_t)(b * 256 + t) * 32 + c4 * 4];
      lv[4*c4+0] = x4.x; lv[4*c4+1] = x4.y; lv[4*c4+2] = x4.z; lv[4*c4+3] = x4.w;
    }
#pragma unroll
    for (int c8 = 0; c8 < 4; ++c8)
      *(bf16x8*)&catB[t * 72 + c8 * 8] = pack8(&lv[c8 * 8]);
#pragma unroll
    for (int c8 = 0; c8 < 4; ++c8)
      *(bf16x8*)&catB[t * 72 + 32 + c8 * 8] = pack8(&outr[c8 * 8]);
  }
  __syncthreads();
  const int w = t >> 6, lane = t & 63, qd = lane >> 4, mcol = lane & 15;
#pragma unroll
  for (int nc = 0; nc < 2; ++nc) {
    floatx4 acc[4][4];
#pragma unroll
    for (int mi = 0; mi < 4; ++mi)
#pragma unroll
      for (int nj = 0; nj < 4; ++nj) acc[mi][nj] = (floatx4)0.f;
#pragma unroll
    for (int s = 0; s < 2; ++s) {
      bf16x8 af[4], bf[4];
#pragma unroll
      for (int mi = 0; mi < 4; ++mi)
        af[mi] = *(const bf16x8*)&catB[(w * 64 + mi * 16 + mcol) * 72 + s * 32 + qd * 8];
#pragma unroll
      for (int nj = 0; nj < 4; ++nj)
        bf[nj] = *(const bf16x8*)&wB[((nc * 4 + nj) * 16 + mcol) * 72 + s * 32 + qd * 8];
#pragma unroll
      for (int mi = 0; mi < 4; ++mi)
#pragma unroll
        for (int nj = 0; nj < 4; ++nj)
          acc[mi][nj] = __builtin_amdgcn_mfma_f32_16x16x32_bf16(af[mi], bf[nj], acc[mi][nj], 0, 0, 0);
    }
#pragma unroll
    for (int mi = 0; mi < 4; ++mi)
#pragma unroll
      for (int nj = 0; nj < 4; ++nj) {
        const int ch = (nc * 4 + nj) * 16 + mcol;
        const float bb = b2o[ch];
        const int cc = ch >> 2, si = (ch >> 1) & 1, sj = ch & 1;
#pragma unroll
        for (int r = 0; r < 4; ++r) {
          const int tok = w * 64 + mi * 16 + qd * 4 + r;
          const int i = tok >> 4, j = tok & 15;
          h[(size_t)b * 32768 + cc * 1024 + (2 * i + si) * 32 + (2 * j + sj)] =
              (__bf16)(acc[mi][nj][r] + bb);
        }
      }
  }
}

// ---------------- K7: fc1 GEMM bf16 MFMA, A-frags direct from global -------
__global__ __launch_bounds__(256) void k7_fc1_gemm(
    const __bf16* __restrict__ A,  // h bf16 [256, 32768]
    const float* __restrict__ Bw,  // fc1_w fp32 [32768, 1024]
    float* __restrict__ part)      // [16][256][1024]
{
  __shared__ __bf16 Bs[32 * 72];
  const int bn = blockIdx.x & 31;
  const int bm = (blockIdx.x >> 5) & 1;
  const int bk = blockIdx.x >> 6;
  const int n0 = bn * 32, m0 = bm * 128, k0 = bk * 2048;
  const int tid = threadIdx.x;
  const int n = tid & 31, koct = tid >> 5;          // staging role
  const int w = tid >> 6, lane = tid & 63;
  const int qd = lane >> 4, mcol = lane & 15;
  floatx4 acc[2][2];
#pragma unroll
  for (int mi = 0; mi < 2; ++mi)
#pragma unroll
    for (int ni = 0; ni < 2; ++ni) acc[mi][ni] = (floatx4)0.f;

  for (int it = 0; it < 32; ++it) {
    const int kk0 = k0 + it * 64;
    float bvals[8];
    const float* brow = Bw + (size_t)(kk0 + koct * 8) * 1024 + n0 + n;
#pragma unroll
    for (int j = 0; j < 8; ++j) bvals[j] = brow[(size_t)j * 1024];
    bf16x8 af[2][2];
#pragma unroll
    for (int mi = 0; mi < 2; ++mi)
#pragma unroll
      for (int s = 0; s < 2; ++s)
        af[mi][s] = *(const bf16x8*)(A + (size_t)(m0 + w * 32 + mi * 16 + mcol) * 32768
                                       + kk0 + s * 32 + qd * 8);
    __syncthreads();
    *(bf16x8*)&Bs[n * 72 + koct * 8] = pack8(bvals);
    __syncthreads();
    bf16x8 bf[2][2];
#pragma unroll
    for (int ni = 0; ni < 2; ++ni)
#pragma unroll
      for (int s = 0; s < 2; ++s)
        bf[ni][s] = *(const bf16x8*)&Bs[(ni * 16 + mcol) * 72 + s * 32 + qd * 8];
#pragma unroll
    for (int s = 0; s < 2; ++s)
#pragma unroll
      for (int mi = 0; mi < 2; ++mi)
#pragma unroll
        for (int ni = 0; ni < 2; ++ni)
          acc[mi][ni] = __builtin_amdgcn_mfma_f32_16x16x32_bf16(af[mi][s], bf[ni][s], acc[mi][ni], 0, 0, 0);
  }
  float* P = part + (size_t)bk * 262144;
#pragma unroll
  for (int mi = 0; mi < 2; ++mi)
#pragma unroll
    for (int ni = 0; ni < 2; ++ni) {
      const int col = n0 + ni * 16 + mcol;
#pragma unroll
      for (int r = 0; r < 4; ++r) {
        const int row = m0 + w * 32 + mi * 16 + qd * 4 + r;
        P[(size_t)row * 1024 + col] = acc[mi][ni][r];
      }
    }
}

// ---------------- K7c+K8: splitK reduce + bias/relu + fc2 ------------------
__global__ __launch_bounds__(256) void k7c8_fc2(
    const float* __restrict__ part, const float* __restrict__ fc1b,
    const float* __restrict__ w2, const float* __restrict__ b2,
    float* __restrict__ out)
{
  const int b = blockIdx.x, t = threadIdx.x;
  const int col4 = t * 4;
  float4 s = make_float4(0.f, 0.f, 0.f, 0.f);
#pragma unroll
  for (int p = 0; p < 16; ++p) {
    const float4 x4 = *(const float4*)&part[(size_t)p * 262144 + (size_t)b * 1024 + col4];
    s.x += x4.x; s.y += x4.y; s.z += x4.z; s.w += x4.w;
  }
  const float4 bb = *(const float4*)&fc1b[col4];
  float a[4] = {fmaxf(s.x + bb.x, 0.f), fmaxf(s.y + bb.y, 0.f),
                fmaxf(s.z + bb.z, 0.f), fmaxf(s.w + bb.w, 0.f)};
  float acc[10];
#pragma unroll
  for (int o = 0; o < 10; ++o) acc[o] = 0.f;
#pragma unroll
  for (int i = 0; i < 4; ++i) {
    const float* wr = w2 + (size_t)(col4 + i) * 10;
#pragma unroll
    for (int o = 0; o < 10; ++o) acc[o] += a[i] * wr[o];
  }
  __shared__ float red[256][10];
#pragma unroll
  for (int o = 0; o < 10; ++o) red[t][o] = acc[o];
  __syncthreads();
  for (int st = 128; st > 0; st >>= 1) {
    if (t < st) {
#pragma unroll
      for (int o = 0; o < 10; ++o) red[t][o] += red[t + st][o];
    }
    __syncthreads();
  }
  if (t < 10) out[b * 10 + t] = red[0][t] + b2[t];
}

// ---------------------------------------------------------------------------
extern "C" void kernel_launch(void* const* d_in, const int* in_sizes, int n_in,
                              void* d_out, int out_size, void* d_ws, size_t ws_size,
                              hipStream_t stream)
{
  const float* x    = (const float*)d_in[0];
  const float* w1c  = (const float*)d_in[1];
  const float* b1c  = (const float*)d_in[2];
  const float* w1q  = (const float*)d_in[3];
  const float* w1k  = (const float*)d_in[4];
  const float* w1v  = (const float*)d_in[5];
  const float* w1o  = (const float*)d_in[6];
  const float* b1o  = (const float*)d_in[7];
  const float* w2c  = (const float*)d_in[8];
  const float* b2c  = (const float*)d_in[9];
  const float* w2q  = (const float*)d_in[10];
  const float* w2k  = (const float*)d_in[11];
  const float* w2v  = (const float*)d_in[12];
  const float* w2o  = (const float*)d_in[13];
  const float* b2o  = (const float*)d_in[14];
  const float* fc1w = (const float*)d_in[15];
  const float* fc1b = (const float*)d_in[16];
  const float* fc2w = (const float*)d_in[17];
  const float* fc2b = (const float*)d_in[18];
  float* out = (float*)d_out;
  float* ws = (float*)d_ws;

  float* q1   = ws + OQ1;
  float* k1   = ws + OK1;
  float* v1   = ws + OV1;
  float* loc1 = ws + OL1;
  float* t2   = ws + OT2;
  float* q2   = ws + OQ2;
  float* k2   = ws + OK2;
  float* v2   = ws + OV2;
  float* loc2 = ws + OL2;
  __bf16* h   = (__bf16*)(ws + OH);
  float* prt  = ws + OPART;

  k1_qkv1<<<16384, 256, 0, stream>>>(x, w1q, w1k, w1v, w1c, b1c, q1, k1, v1, loc1);
  attn1_out<<<256, 256, 0, stream>>>(q1, k1, v1, loc1, w1o, b1o, t2);
  k4_qkv2<<<256, 256, 0, stream>>>(t2, w2q, w2k, w2v, w2c, b2c, q2, k2, v2, loc2);
  attn2_out<<<256, 256, 0, stream>>>(q2, k2, v2, loc2, w2o, b2o, h);
  k7_fc1_gemm<<<1024, 256, 0, stream>>>(h, fc1w, prt);
  k7c8_fc2<<<256, 256, 0, stream>>>(prt, fc1b, fc2w, fc2b, out);
}

// Round 7
// 582.253 us; speedup vs baseline: 1.2260x; 1.2260x over previous
//
#include <hip/hip_runtime.h>
#include <math.h>

// ---------------------------------------------------------------------------
// B=256 images, N=256 tokens/image. L1: Cu=12,d=16(dh=4),r=16 -> 64ch.
// L2: Cu=64,d=32(dh=8),r=32 -> 128ch. shuffle(L1) o unshuffle(L2) == identity.
// R7 = R6 with the workspace-overlap bug fixed: h is 4194304 floats
// (5242880..9437184); OPART moved to 9437184 (over dead v2/loc2).
// Small single-purpose kernels (R4/R5 fusion pegged VGPR=256, spilled 400MB).
// Selection-critical path (q/k/t2) stays exact fp32.
// ---------------------------------------------------------------------------

typedef float floatx4 __attribute__((ext_vector_type(4)));
typedef __bf16 bf16x8 __attribute__((ext_vector_type(8)));

// ---- workspace layout (float offsets), peak 62.9 MB ----
static constexpr size_t OQ1 = 0;          // [65536,16] ..1048576
static constexpr size_t OK1 = 1048576;    // ..2097152
static constexpr size_t OV1 = 2097152;    // ..3145728
static constexpr size_t OL1 = 3145728;    // ..4194304
static constexpr size_t OA1 = 4194304;    // ..5242880
static constexpr size_t OT2 = 5242880;    // [65536,64] ..9437184
static constexpr size_t OQ2 = 0;          // [65536,32] ..2097152 (q1/k1 dead)
static constexpr size_t OK2 = 2097152;    // ..4194304 (v1/loc1 dead after proj1)
static constexpr size_t OV2 = 9437184;    // ..11534336
static constexpr size_t OL2 = 11534336;   // ..13631488
static constexpr size_t OA2 = 13631488;   // ..15728640
static constexpr size_t OH  = 5242880;    // h bf16 [256,32768] = 4194304 floats ..9437184 (t2 dead)
static constexpr size_t OPART = 9437184;  // [16][256][1024] ..13631488 (v2/loc2 dead at k7)

__device__ inline bf16x8 pack8(const float* f) {
  bf16x8 v;
#pragma unroll
  for (int i = 0; i < 8; ++i) v[i] = (__bf16)f[i];
  return v;
}

// ---------------- K1: pixel_unshuffle + q/k/v/local projections, layer 1 ----
__global__ __launch_bounds__(256) void k1_qkv1(
    const float* __restrict__ x, const float* __restrict__ w1q,
    const float* __restrict__ w1k, const float* __restrict__ w1v,
    const float* __restrict__ w1c, const float* __restrict__ b1c,
    float* __restrict__ q1, float* __restrict__ k1,
    float* __restrict__ v1, float* __restrict__ loc1)
{
  const int tid = threadIdx.x;
  const int slot = tid >> 6;
  const int lane = tid & 63;
  const int tok = blockIdx.x * 4 + slot;   // b*256+n
  const int b = tok >> 8, n = tok & 255;
  const int i = n >> 4, j = n & 15;
  __shared__ float ts[4][12];
  if (lane < 12) {
    const int c0 = lane >> 2, si = (lane >> 1) & 1, sj = lane & 1;
    ts[slot][lane] = x[((size_t)(b * 3 + c0) * 32 + 2 * i + si) * 32 + 2 * j + sj];
  }
  __syncthreads();
  const int mat = lane >> 4, col = lane & 15;
  const float* W = (mat == 0) ? w1q : (mat == 1) ? w1k : (mat == 2) ? w1v : w1c;
  float acc = 0.f;
#pragma unroll
  for (int c = 0; c < 12; ++c) acc += ts[slot][c] * W[c * 16 + col];
  const size_t o = (size_t)tok * 16 + col;
  if (mat == 0) q1[o] = acc;
  else if (mat == 1) k1[o] = acc;
  else if (mat == 2) v1[o] = acc;
  else loc1[o] = fmaxf(acc + b1c[col], 0.f);
}

// ---------------- attention select+aggregate: 64-thr blocks, 4 blocks/image -
// Block stages the image's full K into LDS (broadcast reads in the scan are
// conflict-free). Thread t owns one token: branchless top-9 (lax.top_k tie
// semantics), then per-head logits/softmax/V-agg gathered from GLOBAL.
template <int D, int DH, int NH>
__global__ __launch_bounds__(64) void attn_sel(
    const float* __restrict__ q, const float* __restrict__ k,
    const float* __restrict__ v, float* __restrict__ agg)
{
  const int b = blockIdx.x >> 2;
  const int t = (blockIdx.x & 3) * 64 + threadIdx.x;
  __shared__ float ks[256 * D];
  const size_t base = (size_t)b * (256 * D);
  for (int idx = threadIdx.x * 4; idx < 256 * D; idx += 256)
    *(float4*)&ks[idx] = *(const float4*)&k[base + idx];
  float qr[D];
  {
    const float4* qrow = (const float4*)&q[base + (size_t)t * D];
#pragma unroll
    for (int c4 = 0; c4 < D / 4; ++c4) {
      const float4 qv = qrow[c4];
      qr[4 * c4 + 0] = qv.x; qr[4 * c4 + 1] = qv.y;
      qr[4 * c4 + 2] = qv.z; qr[4 * c4 + 3] = qv.w;
    }
  }
  __syncthreads();

  float topv[9];
  int topi[9];
#pragma unroll
  for (int r = 0; r < 9; ++r) { topv[r] = -__builtin_inff(); topi[r] = 0; }

#pragma unroll 2
  for (int m = 0; m < 256; ++m) {
    const float4* kr = (const float4*)&ks[m * D];
    float p0 = 0.f, p1 = 0.f, p2 = 0.f, p3 = 0.f;
#pragma unroll
    for (int g = 0; g < D / 16; ++g) {
      const float4 ka = kr[g * 4 + 0], kb = kr[g * 4 + 1];
      const float4 kc = kr[g * 4 + 2], kd = kr[g * 4 + 3];
      p0 += qr[g*16+ 0]*ka.x + qr[g*16+ 1]*ka.y + qr[g*16+ 2]*ka.z + qr[g*16+ 3]*ka.w;
      p1 += qr[g*16+ 4]*kb.x + qr[g*16+ 5]*kb.y + qr[g*16+ 6]*kb.z + qr[g*16+ 7]*kb.w;
      p2 += qr[g*16+ 8]*kc.x + qr[g*16+ 9]*kc.y + qr[g*16+10]*kc.z + qr[g*16+11]*kc.w;
      p3 += qr[g*16+12]*kd.x + qr[g*16+13]*kd.y + qr[g*16+14]*kd.z + qr[g*16+15]*kd.w;
    }
    const float s = (p0 + p1) + (p2 + p3);
    // branchless sorted insert (descending); strict > + ascending-m stream
    // == lax.top_k stable tie semantics.
    bool ci = s > topv[8];
#pragma unroll
    for (int i = 8; i >= 1; --i) {
      const bool cim1 = s > topv[i - 1];
      topv[i] = ci ? (cim1 ? topv[i - 1] : s) : topv[i];
      topi[i] = ci ? (cim1 ? topi[i - 1] : m) : topi[i];
      ci = cim1;
    }
    topv[0] = ci ? s : topv[0];
    topi[0] = ci ? m : topi[0];
  }

  const float scale = (DH == 4) ? 0.5f : 0.35355339059327373f;
  float outr[D];
#pragma unroll
  for (int hh = 0; hh < NH; ++hh) {
    float lg9[9];
#pragma unroll
    for (int kk = 0; kk < 9; ++kk) {
      const float4* kr = (const float4*)&k[base + (size_t)topi[kk] * D + hh * DH];
      float s = 0.f;
#pragma unroll
      for (int u = 0; u < DH / 4; ++u) {
        const float4 ka = kr[u];
        s += qr[hh*DH + u*4 + 0]*ka.x + qr[hh*DH + u*4 + 1]*ka.y +
             qr[hh*DH + u*4 + 2]*ka.z + qr[hh*DH + u*4 + 3]*ka.w;
      }
      lg9[kk] = s * scale;
    }
    float mx = lg9[0];
#pragma unroll
    for (int kk = 1; kk < 9; ++kk) mx = fmaxf(mx, lg9[kk]);
    float sum = 0.f;
#pragma unroll
    for (int kk = 0; kk < 9; ++kk) { lg9[kk] = __expf(lg9[kk] - mx); sum += lg9[kk]; }
    const float inv = 1.f / sum;
    float oacc[DH];
#pragma unroll
    for (int c = 0; c < DH; ++c) oacc[c] = 0.f;
#pragma unroll
    for (int kk = 0; kk < 9; ++kk) {
      const float4* vr = (const float4*)&v[base + (size_t)topi[kk] * D + hh * DH];
      const float w = lg9[kk] * inv;
#pragma unroll
      for (int u = 0; u < DH / 4; ++u) {
        const float4 va = vr[u];
        oacc[u*4+0] += w * va.x; oacc[u*4+1] += w * va.y;
        oacc[u*4+2] += w * va.z; oacc[u*4+3] += w * va.w;
      }
    }
#pragma unroll
    for (int c = 0; c < DH; ++c) outr[hh * DH + c] = oacc[c];
  }
  float4* o = (float4*)&agg[base + (size_t)t * D];
#pragma unroll
  for (int c4 = 0; c4 < D / 4; ++c4)
    o[c4] = make_float4(outr[4*c4], outr[4*c4+1], outr[4*c4+2], outr[4*c4+3]);
}

// ---------------- proj1: t2 = [loc1|agg1] @ W1o + b1o, exact fp32 ----------
__global__ __launch_bounds__(256) void proj1(
    const float* __restrict__ loc1, const float* __restrict__ agg1,
    const float* __restrict__ w1o, const float* __restrict__ b1o,
    float* __restrict__ t2)
{
  const int tid = threadIdx.x;
  const int tok = blockIdx.x * 256 + tid;
  __shared__ float wS[32 * 64];   // 8 KB
  __shared__ float bS[64];
  for (int idx = tid * 4; idx < 2048; idx += 1024)
    *(float4*)&wS[idx] = *(const float4*)&w1o[idx];
  if (tid < 64) bS[tid] = b1o[tid];
  float cat[32];
#pragma unroll
  for (int c4 = 0; c4 < 4; ++c4) {
    const float4 l4 = *(const float4*)&loc1[(size_t)tok * 16 + c4 * 4];
    cat[4*c4+0] = l4.x; cat[4*c4+1] = l4.y; cat[4*c4+2] = l4.z; cat[4*c4+3] = l4.w;
    const float4 a4 = *(const float4*)&agg1[(size_t)tok * 16 + c4 * 4];
    cat[16+4*c4+0] = a4.x; cat[16+4*c4+1] = a4.y; cat[16+4*c4+2] = a4.z; cat[16+4*c4+3] = a4.w;
  }
  __syncthreads();
  float acc[64];
#pragma unroll
  for (int o = 0; o < 64; ++o) acc[o] = 0.f;
#pragma unroll 4
  for (int c = 0; c < 32; ++c) {
    const float cv = cat[c];
#pragma unroll
    for (int o4 = 0; o4 < 16; ++o4) {
      const float4 w4 = *(const float4*)&wS[c * 64 + o4 * 4];
      acc[o4*4+0] += cv * w4.x; acc[o4*4+1] += cv * w4.y;
      acc[o4*4+2] += cv * w4.z; acc[o4*4+3] += cv * w4.w;
    }
  }
  float* dst = t2 + (size_t)tok * 64;
#pragma unroll
  for (int o4 = 0; o4 < 16; ++o4)
    *(float4*)&dst[o4 * 4] = make_float4(acc[o4*4] + bS[o4*4], acc[o4*4+1] + bS[o4*4+1],
                                         acc[o4*4+2] + bS[o4*4+2], acc[o4*4+3] + bS[o4*4+3]);
}

// ---------------- K4: layer-2 q/k/v/local projections, exact fp32 ----------
// 64 tokens/block, thread = (token, matrix): acc[32], ~60 VGPR.
__global__ __launch_bounds__(256) void k4_qkv2(
    const float* __restrict__ t2, const float* __restrict__ w2q,
    const float* __restrict__ w2k, const float* __restrict__ w2v,
    const float* __restrict__ w2c, const float* __restrict__ b2c,
    float* __restrict__ q2, float* __restrict__ k2,
    float* __restrict__ v2, float* __restrict__ loc2)
{
  const int blk = blockIdx.x;       // 1024 blocks x 64 tokens
  const int tid = threadIdx.x;
  __shared__ float t2S[64 * 68];    // 17.4 KB
  __shared__ float wS[4 * 2312];    // 37 KB
  __shared__ float bS[32];
  for (int idx = tid * 4; idx < 4096; idx += 1024) {
    const float4 vv = *(const float4*)&t2[(size_t)blk * 4096 + idx];
    *(float4*)&t2S[(idx >> 6) * 68 + (idx & 63)] = vv;
  }
  for (int idx = tid * 4; idx < 2048; idx += 1024) {
    const int c = idx >> 5, col = idx & 31;
    *(float4*)&wS[0 * 2312 + c * 36 + col] = *(const float4*)&w2q[idx];
    *(float4*)&wS[1 * 2312 + c * 36 + col] = *(const float4*)&w2k[idx];
    *(float4*)&wS[2 * 2312 + c * 36 + col] = *(const float4*)&w2v[idx];
    *(float4*)&wS[3 * 2312 + c * 36 + col] = *(const float4*)&w2c[idx];
  }
  if (tid < 32) bS[tid] = b2c[tid];
  __syncthreads();
  const int tq = tid >> 2, mat = tid & 3;
  const float* wm = &wS[mat * 2312];
  float acc[32];
#pragma unroll
  for (int e = 0; e < 32; ++e) acc[e] = 0.f;
#pragma unroll 4
  for (int c = 0; c < 64; ++c) {
    const float tv = t2S[tq * 68 + c];
#pragma unroll
    for (int o4 = 0; o4 < 8; ++o4) {
      const float4 w4 = *(const float4*)&wm[c * 36 + o4 * 4];
      acc[o4*4+0] += tv * w4.x; acc[o4*4+1] += tv * w4.y;
      acc[o4*4+2] += tv * w4.z; acc[o4*4+3] += tv * w4.w;
    }
  }
  if (mat == 3) {
#pragma unroll
    for (int e = 0; e < 32; ++e) acc[e] = fmaxf(acc[e] + bS[e], 0.f);
  }
  float* dst = (mat == 0) ? q2 : (mat == 1) ? k2 : (mat == 2) ? v2 : loc2;
  float* drow = dst + (size_t)(blk * 64 + tq) * 32;
#pragma unroll
  for (int o4 = 0; o4 < 8; ++o4)
    *(float4*)&drow[o4 * 4] = make_float4(acc[o4*4], acc[o4*4+1], acc[o4*4+2], acc[o4*4+3]);
}

// ---------------- proj2h: h = [loc2|agg2] @ W2o + b2o (bf16 MFMA) ----------
// + pixel_shuffle scatter into bf16 h. 1 image/block.
__global__ __launch_bounds__(256) void proj2h(
    const float* __restrict__ loc2, const float* __restrict__ agg2,
    const float* __restrict__ w2o, const float* __restrict__ b2o,
    __bf16* __restrict__ h)
{
  const int b = blockIdx.x;
  const int t = threadIdx.x;
  __shared__ __bf16 catB[256 * 72];   // 36.9 KB
  __shared__ __bf16 wB[128 * 72];     // 18.4 KB  [n][k]
  {  // stage W2o transposed to bf16 [n][k]
    const int n = t >> 1, khalf = t & 1;
    float wv[32];
#pragma unroll
    for (int j = 0; j < 32; ++j) wv[j] = w2o[(size_t)(khalf * 32 + j) * 128 + n];
#pragma unroll
    for (int j8 = 0; j8 < 4; ++j8)
      *(bf16x8*)&wB[n * 72 + khalf * 32 + j8 * 8] = pack8(&wv[j8 * 8]);
  }
  {  // stage cat row (loc2 | agg2) as bf16
    float lv[32];
#pragma unroll
    for (int c4 = 0; c4 < 8; ++c4) {
      const float4 x4 = *(const float4*)&loc2[(size_t)(b * 256 + t) * 32 + c4 * 4];
      lv[4*c4+0] = x4.x; lv[4*c4+1] = x4.y; lv[4*c4+2] = x4.z; lv[4*c4+3] = x4.w;
    }
#pragma unroll
    for (int c8 = 0; c8 < 4; ++c8)
      *(bf16x8*)&catB[t * 72 + c8 * 8] = pack8(&lv[c8 * 8]);
#pragma unroll
    for (int c4 = 0; c4 < 8; ++c4) {
      const float4 x4 = *(const float4*)&agg2[(size_t)(b * 256 + t) * 32 + c4 * 4];
      lv[4*c4+0] = x4.x; lv[4*c4+1] = x4.y; lv[4*c4+2] = x4.z; lv[4*c4+3] = x4.w;
    }
#pragma unroll
    for (int c8 = 0; c8 < 4; ++c8)
      *(bf16x8*)&catB[t * 72 + 32 + c8 * 8] = pack8(&lv[c8 * 8]);
  }
  __syncthreads();
  const int w = t >> 6, lane = t & 63, qd = lane >> 4, mcol = lane & 15;
#pragma unroll
  for (int nc = 0; nc < 2; ++nc) {
    floatx4 acc[4][4];
#pragma unroll
    for (int mi = 0; mi < 4; ++mi)
#pragma unroll
      for (int nj = 0; nj < 4; ++nj) acc[mi][nj] = (floatx4)0.f;
#pragma unroll
    for (int s = 0; s < 2; ++s) {
      bf16x8 af[4], bf[4];
#pragma unroll
      for (int mi = 0; mi < 4; ++mi)
        af[mi] = *(const bf16x8*)&catB[(w * 64 + mi * 16 + mcol) * 72 + s * 32 + qd * 8];
#pragma unroll
      for (int nj = 0; nj < 4; ++nj)
        bf[nj] = *(const bf16x8*)&wB[((nc * 4 + nj) * 16 + mcol) * 72 + s * 32 + qd * 8];
#pragma unroll
      for (int mi = 0; mi < 4; ++mi)
#pragma unroll
        for (int nj = 0; nj < 4; ++nj)
          acc[mi][nj] = __builtin_amdgcn_mfma_f32_16x16x32_bf16(af[mi], bf[nj], acc[mi][nj], 0, 0, 0);
    }
#pragma unroll
    for (int mi = 0; mi < 4; ++mi)
#pragma unroll
      for (int nj = 0; nj < 4; ++nj) {
        const int ch = (nc * 4 + nj) * 16 + mcol;
        const float bb = b2o[ch];
        const int cc = ch >> 2, si = (ch >> 1) & 1, sj = ch & 1;
#pragma unroll
        for (int r = 0; r < 4; ++r) {
          const int tok = w * 64 + mi * 16 + qd * 4 + r;
          const int i = tok >> 4, j = tok & 15;
          h[(size_t)b * 32768 + cc * 1024 + (2 * i + si) * 32 + (2 * j + sj)] =
              (__bf16)(acc[mi][nj][r] + bb);
        }
      }
  }
}

// ---------------- K7: fc1 GEMM bf16 MFMA, A-frags direct from global -------
__global__ __launch_bounds__(256) void k7_fc1_gemm(
    const __bf16* __restrict__ A,  // h bf16 [256, 32768]
    const float* __restrict__ Bw,  // fc1_w fp32 [32768, 1024]
    float* __restrict__ part)      // [16][256][1024]
{
  __shared__ __bf16 Bs[32 * 72];
  const int bn = blockIdx.x & 31;
  const int bm = (blockIdx.x >> 5) & 1;
  const int bk = blockIdx.x >> 6;
  const int n0 = bn * 32, m0 = bm * 128, k0 = bk * 2048;
  const int tid = threadIdx.x;
  const int n = tid & 31, koct = tid >> 5;
  const int w = tid >> 6, lane = tid & 63;
  const int qd = lane >> 4, mcol = lane & 15;
  floatx4 acc[2][2];
#pragma unroll
  for (int mi = 0; mi < 2; ++mi)
#pragma unroll
    for (int ni = 0; ni < 2; ++ni) acc[mi][ni] = (floatx4)0.f;

  for (int it = 0; it < 32; ++it) {
    const int kk0 = k0 + it * 64;
    float bvals[8];
    const float* brow = Bw + (size_t)(kk0 + koct * 8) * 1024 + n0 + n;
#pragma unroll
    for (int j = 0; j < 8; ++j) bvals[j] = brow[(size_t)j * 1024];
    bf16x8 af[2][2];
#pragma unroll
    for (int mi = 0; mi < 2; ++mi)
#pragma unroll
      for (int s = 0; s < 2; ++s)
        af[mi][s] = *(const bf16x8*)(A + (size_t)(m0 + w * 32 + mi * 16 + mcol) * 32768
                                       + kk0 + s * 32 + qd * 8);
    __syncthreads();
    *(bf16x8*)&Bs[n * 72 + koct * 8] = pack8(bvals);
    __syncthreads();
    bf16x8 bf[2][2];
#pragma unroll
    for (int ni = 0; ni < 2; ++ni)
#pragma unroll
      for (int s = 0; s < 2; ++s)
        bf[ni][s] = *(const bf16x8*)&Bs[(ni * 16 + mcol) * 72 + s * 32 + qd * 8];
#pragma unroll
    for (int s = 0; s < 2; ++s)
#pragma unroll
      for (int mi = 0; mi < 2; ++mi)
#pragma unroll
        for (int ni = 0; ni < 2; ++ni)
          acc[mi][ni] = __builtin_amdgcn_mfma_f32_16x16x32_bf16(af[mi][s], bf[ni][s], acc[mi][ni], 0, 0, 0);
  }
  float* P = part + (size_t)bk * 262144;
#pragma unroll
  for (int mi = 0; mi < 2; ++mi)
#pragma unroll
    for (int ni = 0; ni < 2; ++ni) {
      const int col = n0 + ni * 16 + mcol;
#pragma unroll
      for (int r = 0; r < 4; ++r) {
        const int row = m0 + w * 32 + mi * 16 + qd * 4 + r;
        P[(size_t)row * 1024 + col] = acc[mi][ni][r];
      }
    }
}

// ---------------- K7c+K8: splitK reduce + bias/relu + fc2 ------------------
__global__ __launch_bounds__(256) void k7c8_fc2(
    const float* __restrict__ part, const float* __restrict__ fc1b,
    const float* __restrict__ w2, const float* __restrict__ b2,
    float* __restrict__ out)
{
  const int b = blockIdx.x, t = threadIdx.x;
  const int col4 = t * 4;
  float4 s = make_float4(0.f, 0.f, 0.f, 0.f);
#pragma unroll
  for (int p = 0; p < 16; ++p) {
    const float4 x4 = *(const float4*)&part[(size_t)p * 262144 + (size_t)b * 1024 + col4];
    s.x += x4.x; s.y += x4.y; s.z += x4.z; s.w += x4.w;
  }
  const float4 bb = *(const float4*)&fc1b[col4];
  float a[4] = {fmaxf(s.x + bb.x, 0.f), fmaxf(s.y + bb.y, 0.f),
                fmaxf(s.z + bb.z, 0.f), fmaxf(s.w + bb.w, 0.f)};
  float acc[10];
#pragma unroll
  for (int o = 0; o < 10; ++o) acc[o] = 0.f;
#pragma unroll
  for (int i = 0; i < 4; ++i) {
    const float* wr = w2 + (size_t)(col4 + i) * 10;
#pragma unroll
    for (int o = 0; o < 10; ++o) acc[o] += a[i] * wr[o];
  }
  __shared__ float red[256][10];
#pragma unroll
  for (int o = 0; o < 10; ++o) red[t][o] = acc[o];
  __syncthreads();
  for (int st = 128; st > 0; st >>= 1) {
    if (t < st) {
#pragma unroll
      for (int o = 0; o < 10; ++o) red[t][o] += red[t + st][o];
    }
    __syncthreads();
  }
  if (t < 10) out[b * 10 + t] = red[0][t] + b2[t];
}

// ---------------------------------------------------------------------------
extern "C" void kernel_launch(void* const* d_in, const int* in_sizes, int n_in,
                              void* d_out, int out_size, void* d_ws, size_t ws_size,
                              hipStream_t stream)
{
  const float* x    = (const float*)d_in[0];
  const float* w1c  = (const float*)d_in[1];
  const float* b1c  = (const float*)d_in[2];
  const float* w1q  = (const float*)d_in[3];
  const float* w1k  = (const float*)d_in[4];
  const float* w1v  = (const float*)d_in[5];
  const float* w1o  = (const float*)d_in[6];
  const float* b1o  = (const float*)d_in[7];
  const float* w2c  = (const float*)d_in[8];
  const float* b2c  = (const float*)d_in[9];
  const float* w2q  = (const float*)d_in[10];
  const float* w2k  = (const float*)d_in[11];
  const float* w2v  = (const float*)d_in[12];
  const float* w2o  = (const float*)d_in[13];
  const float* b2o  = (const float*)d_in[14];
  const float* fc1w = (const float*)d_in[15];
  const float* fc1b = (const float*)d_in[16];
  const float* fc2w = (const float*)d_in[17];
  const float* fc2b = (const float*)d_in[18];
  float* out = (float*)d_out;
  float* ws = (float*)d_ws;

  float* q1   = ws + OQ1;
  float* k1   = ws + OK1;
  float* v1   = ws + OV1;
  float* loc1 = ws + OL1;
  float* agg1 = ws + OA1;
  float* t2   = ws + OT2;
  float* q2   = ws + OQ2;
  float* k2   = ws + OK2;
  float* v2   = ws + OV2;
  float* loc2 = ws + OL2;
  float* agg2 = ws + OA2;
  __bf16* h   = (__bf16*)(ws + OH);
  float* prt  = ws + OPART;

  k1_qkv1<<<16384, 256, 0, stream>>>(x, w1q, w1k, w1v, w1c, b1c, q1, k1, v1, loc1);
  attn_sel<16, 4, 4><<<1024, 64, 0, stream>>>(q1, k1, v1, agg1);
  proj1<<<256, 256, 0, stream>>>(loc1, agg1, w1o, b1o, t2);
  k4_qkv2<<<1024, 256, 0, stream>>>(t2, w2q, w2k, w2v, w2c, b2c, q2, k2, v2, loc2);
  attn_sel<32, 8, 4><<<1024, 64, 0, stream>>>(q2, k2, v2, agg2);
  proj2h<<<256, 256, 0, stream>>>(loc2, agg2, w2o, b2o, h);
  k7_fc1_gemm<<<1024, 256, 0, stream>>>(h, fc1w, prt);
  k7c8_fc2<<<256, 256, 0, stream>>>(prt, fc1b, fc2w, fc2b, out);
}

// Round 8
// 473.603 us; speedup vs baseline: 1.5073x; 1.2294x over previous
//
#include <hip/hip_runtime.h>
#include <math.h>

// ---------------------------------------------------------------------------
// B=256 images, N=256 tokens/image. L1: Cu=12,d=16(dh=4),r=16 -> 64ch.
// L2: Cu=64,d=32(dh=8),r=32 -> 128ch. shuffle(L1) o unshuffle(L2) == identity.
// R8: attn_sel = 4-way candidate split (256 thr, 64 tok/block): wave w scans
// cands w*64..+63 -> per-thread top-9 -> wave-0 merge (quarter-order stream
// keeps lax.top_k tie semantics) -> phases 2/3 parallel by head.
// k7 = one block covers all 256 M rows (halves fc1_w HBM: 268->134 MB).
// Selection-critical path (q/k/t2) stays exact fp32.
// ---------------------------------------------------------------------------

typedef float floatx4 __attribute__((ext_vector_type(4)));
typedef __bf16 bf16x8 __attribute__((ext_vector_type(8)));

// ---- workspace layout (float offsets), peak 62.9 MB ----
static constexpr size_t OQ1 = 0;          // [65536,16] ..1048576
static constexpr size_t OK1 = 1048576;    // ..2097152
static constexpr size_t OV1 = 2097152;    // ..3145728
static constexpr size_t OL1 = 3145728;    // ..4194304
static constexpr size_t OA1 = 4194304;    // ..5242880
static constexpr size_t OT2 = 5242880;    // [65536,64] ..9437184
static constexpr size_t OQ2 = 0;          // [65536,32] ..2097152 (q1/k1 dead)
static constexpr size_t OK2 = 2097152;    // ..4194304 (v1/loc1 dead after proj1)
static constexpr size_t OV2 = 9437184;    // ..11534336
static constexpr size_t OL2 = 11534336;   // ..13631488
static constexpr size_t OA2 = 13631488;   // ..15728640
static constexpr size_t OH  = 5242880;    // h bf16 [256,32768] = 4194304 floats ..9437184 (t2 dead)
static constexpr size_t OPART = 9437184;  // [16][256][1024] ..13631488 (v2/loc2 dead at k7)

__device__ inline bf16x8 pack8(const float* f) {
  bf16x8 v;
#pragma unroll
  for (int i = 0; i < 8; ++i) v[i] = (__bf16)f[i];
  return v;
}

// ---------------- K1: pixel_unshuffle + q/k/v/local projections, layer 1 ----
__global__ __launch_bounds__(256) void k1_qkv1(
    const float* __restrict__ x, const float* __restrict__ w1q,
    const float* __restrict__ w1k, const float* __restrict__ w1v,
    const float* __restrict__ w1c, const float* __restrict__ b1c,
    float* __restrict__ q1, float* __restrict__ k1,
    float* __restrict__ v1, float* __restrict__ loc1)
{
  const int tid = threadIdx.x;
  const int slot = tid >> 6;
  const int lane = tid & 63;
  const int tok = blockIdx.x * 4 + slot;   // b*256+n
  const int b = tok >> 8, n = tok & 255;
  const int i = n >> 4, j = n & 15;
  __shared__ float ts[4][12];
  if (lane < 12) {
    const int c0 = lane >> 2, si = (lane >> 1) & 1, sj = lane & 1;
    ts[slot][lane] = x[((size_t)(b * 3 + c0) * 32 + 2 * i + si) * 32 + 2 * j + sj];
  }
  __syncthreads();
  const int mat = lane >> 4, col = lane & 15;
  const float* W = (mat == 0) ? w1q : (mat == 1) ? w1k : (mat == 2) ? w1v : w1c;
  float acc = 0.f;
#pragma unroll
  for (int c = 0; c < 12; ++c) acc += ts[slot][c] * W[c * 16 + col];
  const size_t o = (size_t)tok * 16 + col;
  if (mat == 0) q1[o] = acc;
  else if (mat == 1) k1[o] = acc;
  else if (mat == 2) v1[o] = acc;
  else loc1[o] = fmaxf(acc + b1c[col], 0.f);
}

// ---------------- attention select+aggregate: 4-way candidate split --------
// 256 thr / 64 tokens per block; thread = (token tok, quarter qt).
// Wave qt scans candidates qt*64..qt*64+63 for its token -> local top-9
// (strict >, ascending m == lax.top_k tie semantics within the quarter).
// Wave 0 merges the 4 sorted lists streamed in quarter order (ascending
// index across quarters, arrival order preserves ties) -> final 9.
// Phases 2/3: thread handles head qt of its token; gathers from global (L2).
template <int D, int DH, int NH>
__global__ __launch_bounds__(256) void attn_sel(
    const float* __restrict__ q, const float* __restrict__ k,
    const float* __restrict__ v, float* __restrict__ agg)
{
  const int blk = blockIdx.x;
  const int b = blk >> 2;              // image
  const int t0 = (blk & 3) * 64;       // token base within image
  const int tid = threadIdx.x;
  const int tok = tid & 63;            // local token
  const int qt = tid >> 6;             // candidate quarter == wave == head
  __shared__ float ks[256 * D];
  __shared__ float mvS[4 * 576];       // [qq][tok*9+r]
  __shared__ int   miS[4 * 576];
  __shared__ int   selS[576];          // [tok*9+kk]
  const size_t base = (size_t)b * (256 * D);
  for (int idx = tid * 4; idx < 256 * D; idx += 1024)
    *(float4*)&ks[idx] = *(const float4*)&k[base + idx];
  float qr[D];
  {
    const float4* qrow = (const float4*)&q[base + (size_t)(t0 + tok) * D];
#pragma unroll
    for (int c4 = 0; c4 < D / 4; ++c4) {
      const float4 qv = qrow[c4];
      qr[4 * c4 + 0] = qv.x; qr[4 * c4 + 1] = qv.y;
      qr[4 * c4 + 2] = qv.z; qr[4 * c4 + 3] = qv.w;
    }
  }
  __syncthreads();

  float topv[9];
  int topi[9];
#pragma unroll
  for (int r = 0; r < 9; ++r) { topv[r] = -__builtin_inff(); topi[r] = 0; }

#pragma unroll 2
  for (int j = 0; j < 64; ++j) {
    const int m = qt * 64 + j;
    const float4* kr = (const float4*)&ks[m * D];
    float p0 = 0.f, p1 = 0.f, p2 = 0.f, p3 = 0.f;
#pragma unroll
    for (int g = 0; g < D / 16; ++g) {
      const float4 ka = kr[g * 4 + 0], kb = kr[g * 4 + 1];
      const float4 kc = kr[g * 4 + 2], kd = kr[g * 4 + 3];
      p0 += qr[g*16+ 0]*ka.x + qr[g*16+ 1]*ka.y + qr[g*16+ 2]*ka.z + qr[g*16+ 3]*ka.w;
      p1 += qr[g*16+ 4]*kb.x + qr[g*16+ 5]*kb.y + qr[g*16+ 6]*kb.z + qr[g*16+ 7]*kb.w;
      p2 += qr[g*16+ 8]*kc.x + qr[g*16+ 9]*kc.y + qr[g*16+10]*kc.z + qr[g*16+11]*kc.w;
      p3 += qr[g*16+12]*kd.x + qr[g*16+13]*kd.y + qr[g*16+14]*kd.z + qr[g*16+15]*kd.w;
    }
    const float s = (p0 + p1) + (p2 + p3);
    bool ci = s > topv[8];
#pragma unroll
    for (int i = 8; i >= 1; --i) {
      const bool cim1 = s > topv[i - 1];
      topv[i] = ci ? (cim1 ? topv[i - 1] : s) : topv[i];
      topi[i] = ci ? (cim1 ? topi[i - 1] : m) : topi[i];
      ci = cim1;
    }
    topv[0] = ci ? s : topv[0];
    topi[0] = ci ? m : topi[0];
  }
#pragma unroll
  for (int r = 0; r < 9; ++r) {
    mvS[qt * 576 + tok * 9 + r] = topv[r];
    miS[qt * 576 + tok * 9 + r] = topi[r];
  }
  __syncthreads();
  if (qt == 0) {   // wave 0 merges 36 -> 9 for its token
    float fv[9];
    int fi[9];
#pragma unroll
    for (int r = 0; r < 9; ++r) { fv[r] = -__builtin_inff(); fi[r] = 0; }
#pragma unroll
    for (int qq = 0; qq < 4; ++qq)
#pragma unroll
      for (int r = 0; r < 9; ++r) {
        const float s = mvS[qq * 576 + tok * 9 + r];
        const int ix = miS[qq * 576 + tok * 9 + r];
        bool ci = s > fv[8];
#pragma unroll
        for (int i = 8; i >= 1; --i) {
          const bool cim1 = s > fv[i - 1];
          fv[i] = ci ? (cim1 ? fv[i - 1] : s) : fv[i];
          fi[i] = ci ? (cim1 ? fi[i - 1] : ix) : fi[i];
          ci = cim1;
        }
        fv[0] = ci ? s : fv[0];
        fi[0] = ci ? ix : fi[0];
      }
#pragma unroll
    for (int r = 0; r < 9; ++r) selS[tok * 9 + r] = fi[r];
  }
  __syncthreads();

  // phases 2/3: this thread handles head hh = qt of token tok.
  const int hh = qt;
  const float scale = (DH == 4) ? 0.5f : 0.35355339059327373f;
  int sel9[9];
#pragma unroll
  for (int kk = 0; kk < 9; ++kk) sel9[kk] = selS[tok * 9 + kk];
  float lg9[9];
#pragma unroll
  for (int kk = 0; kk < 9; ++kk) {
    const float4* kr = (const float4*)&k[base + (size_t)sel9[kk] * D + hh * DH];
    float s = 0.f;
#pragma unroll
    for (int u = 0; u < DH / 4; ++u) {
      const float4 ka = kr[u];
      s += qr[hh*DH + u*4 + 0]*ka.x + qr[hh*DH + u*4 + 1]*ka.y +
           qr[hh*DH + u*4 + 2]*ka.z + qr[hh*DH + u*4 + 3]*ka.w;
    }
    lg9[kk] = s * scale;
  }
  float mx = lg9[0];
#pragma unroll
  for (int kk = 1; kk < 9; ++kk) mx = fmaxf(mx, lg9[kk]);
  float sum = 0.f;
#pragma unroll
  for (int kk = 0; kk < 9; ++kk) { lg9[kk] = __expf(lg9[kk] - mx); sum += lg9[kk]; }
  const float inv = 1.f / sum;
  float oacc[DH];
#pragma unroll
  for (int c = 0; c < DH; ++c) oacc[c] = 0.f;
#pragma unroll
  for (int kk = 0; kk < 9; ++kk) {
    const float4* vr = (const float4*)&v[base + (size_t)sel9[kk] * D + hh * DH];
    const float w = lg9[kk] * inv;
#pragma unroll
    for (int u = 0; u < DH / 4; ++u) {
      const float4 va = vr[u];
      oacc[u*4+0] += w * va.x; oacc[u*4+1] += w * va.y;
      oacc[u*4+2] += w * va.z; oacc[u*4+3] += w * va.w;
    }
  }
  float* o = &agg[base + (size_t)(t0 + tok) * D + hh * DH];
#pragma unroll
  for (int u = 0; u < DH / 4; ++u)
    *(float4*)&o[u * 4] = make_float4(oacc[u*4], oacc[u*4+1], oacc[u*4+2], oacc[u*4+3]);
}

// ---------------- proj1: t2 = [loc1|agg1] @ W1o + b1o, exact fp32 ----------
__global__ __launch_bounds__(256) void proj1(
    const float* __restrict__ loc1, const float* __restrict__ agg1,
    const float* __restrict__ w1o, const float* __restrict__ b1o,
    float* __restrict__ t2)
{
  const int tid = threadIdx.x;
  const int tok = blockIdx.x * 256 + tid;
  __shared__ float wS[32 * 64];   // 8 KB
  __shared__ float bS[64];
  for (int idx = tid * 4; idx < 2048; idx += 1024)
    *(float4*)&wS[idx] = *(const float4*)&w1o[idx];
  if (tid < 64) bS[tid] = b1o[tid];
  float cat[32];
#pragma unroll
  for (int c4 = 0; c4 < 4; ++c4) {
    const float4 l4 = *(const float4*)&loc1[(size_t)tok * 16 + c4 * 4];
    cat[4*c4+0] = l4.x; cat[4*c4+1] = l4.y; cat[4*c4+2] = l4.z; cat[4*c4+3] = l4.w;
    const float4 a4 = *(const float4*)&agg1[(size_t)tok * 16 + c4 * 4];
    cat[16+4*c4+0] = a4.x; cat[16+4*c4+1] = a4.y; cat[16+4*c4+2] = a4.z; cat[16+4*c4+3] = a4.w;
  }
  __syncthreads();
  float acc[64];
#pragma unroll
  for (int o = 0; o < 64; ++o) acc[o] = 0.f;
#pragma unroll 4
  for (int c = 0; c < 32; ++c) {
    const float cv = cat[c];
#pragma unroll
    for (int o4 = 0; o4 < 16; ++o4) {
      const float4 w4 = *(const float4*)&wS[c * 64 + o4 * 4];
      acc[o4*4+0] += cv * w4.x; acc[o4*4+1] += cv * w4.y;
      acc[o4*4+2] += cv * w4.z; acc[o4*4+3] += cv * w4.w;
    }
  }
  float* dst = t2 + (size_t)tok * 64;
#pragma unroll
  for (int o4 = 0; o4 < 16; ++o4)
    *(float4*)&dst[o4 * 4] = make_float4(acc[o4*4] + bS[o4*4], acc[o4*4+1] + bS[o4*4+1],
                                         acc[o4*4+2] + bS[o4*4+2], acc[o4*4+3] + bS[o4*4+3]);
}

// ---------------- K4: layer-2 q/k/v/local projections, exact fp32 ----------
__global__ __launch_bounds__(256) void k4_qkv2(
    const float* __restrict__ t2, const float* __restrict__ w2q,
    const float* __restrict__ w2k, const float* __restrict__ w2v,
    const float* __restrict__ w2c, const float* __restrict__ b2c,
    float* __restrict__ q2, float* __restrict__ k2,
    float* __restrict__ v2, float* __restrict__ loc2)
{
  const int blk = blockIdx.x;       // 1024 blocks x 64 tokens
  const int tid = threadIdx.x;
  __shared__ float t2S[64 * 68];    // 17.4 KB
  __shared__ float wS[4 * 2312];    // 37 KB
  __shared__ float bS[32];
  for (int idx = tid * 4; idx < 4096; idx += 1024) {
    const float4 vv = *(const float4*)&t2[(size_t)blk * 4096 + idx];
    *(float4*)&t2S[(idx >> 6) * 68 + (idx & 63)] = vv;
  }
  for (int idx = tid * 4; idx < 2048; idx += 1024) {
    const int c = idx >> 5, col = idx & 31;
    *(float4*)&wS[0 * 2312 + c * 36 + col] = *(const float4*)&w2q[idx];
    *(float4*)&wS[1 * 2312 + c * 36 + col] = *(const float4*)&w2k[idx];
    *(float4*)&wS[2 * 2312 + c * 36 + col] = *(const float4*)&w2v[idx];
    *(float4*)&wS[3 * 2312 + c * 36 + col] = *(const float4*)&w2c[idx];
  }
  if (tid < 32) bS[tid] = b2c[tid];
  __syncthreads();
  const int tq = tid >> 2, mat = tid & 3;
  const float* wm = &wS[mat * 2312];
  float acc[32];
#pragma unroll
  for (int e = 0; e < 32; ++e) acc[e] = 0.f;
#pragma unroll 4
  for (int c = 0; c < 64; ++c) {
    const float tv = t2S[tq * 68 + c];
#pragma unroll
    for (int o4 = 0; o4 < 8; ++o4) {
      const float4 w4 = *(const float4*)&wm[c * 36 + o4 * 4];
      acc[o4*4+0] += tv * w4.x; acc[o4*4+1] += tv * w4.y;
      acc[o4*4+2] += tv * w4.z; acc[o4*4+3] += tv * w4.w;
    }
  }
  if (mat == 3) {
#pragma unroll
    for (int e = 0; e < 32; ++e) acc[e] = fmaxf(acc[e] + bS[e], 0.f);
  }
  float* dst = (mat == 0) ? q2 : (mat == 1) ? k2 : (mat == 2) ? v2 : loc2;
  float* drow = dst + (size_t)(blk * 64 + tq) * 32;
#pragma unroll
  for (int o4 = 0; o4 < 8; ++o4)
    *(float4*)&drow[o4 * 4] = make_float4(acc[o4*4], acc[o4*4+1], acc[o4*4+2], acc[o4*4+3]);
}

// ---------------- proj2h: h = [loc2|agg2] @ W2o + b2o (bf16 MFMA) ----------
__global__ __launch_bounds__(256) void proj2h(
    const float* __restrict__ loc2, const float* __restrict__ agg2,
    const float* __restrict__ w2o, const float* __restrict__ b2o,
    __bf16* __restrict__ h)
{
  const int b = blockIdx.x;
  const int t = threadIdx.x;
  __shared__ __bf16 catB[256 * 72];   // 36.9 KB
  __shared__ __bf16 wB[128 * 72];     // 18.4 KB  [n][k]
  {  // stage W2o transposed to bf16 [n][k]
    const int n = t >> 1, khalf = t & 1;
    float wv[32];
#pragma unroll
    for (int j = 0; j < 32; ++j) wv[j] = w2o[(size_t)(khalf * 32 + j) * 128 + n];
#pragma unroll
    for (int j8 = 0; j8 < 4; ++j8)
      *(bf16x8*)&wB[n * 72 + khalf * 32 + j8 * 8] = pack8(&wv[j8 * 8]);
  }
  {  // stage cat row (loc2 | agg2) as bf16
    float lv[32];
#pragma unroll
    for (int c4 = 0; c4 < 8; ++c4) {
      const float4 x4 = *(const float4*)&loc2[(size_t)(b * 256 + t) * 32 + c4 * 4];
      lv[4*c4+0] = x4.x; lv[4*c4+1] = x4.y; lv[4*c4+2] = x4.z; lv[4*c4+3] = x4.w;
    }
#pragma unroll
    for (int c8 = 0; c8 < 4; ++c8)
      *(bf16x8*)&catB[t * 72 + c8 * 8] = pack8(&lv[c8 * 8]);
#pragma unroll
    for (int c4 = 0; c4 < 8; ++c4) {
      const float4 x4 = *(const float4*)&agg2[(size_t)(b * 256 + t) * 32 + c4 * 4];
      lv[4*c4+0] = x4.x; lv[4*c4+1] = x4.y; lv[4*c4+2] = x4.z; lv[4*c4+3] = x4.w;
    }
#pragma unroll
    for (int c8 = 0; c8 < 4; ++c8)
      *(bf16x8*)&catB[t * 72 + 32 + c8 * 8] = pack8(&lv[c8 * 8]);
  }
  __syncthreads();
  const int w = t >> 6, lane = t & 63, qd = lane >> 4, mcol = lane & 15;
#pragma unroll
  for (int nc = 0; nc < 2; ++nc) {
    floatx4 acc[4][4];
#pragma unroll
    for (int mi = 0; mi < 4; ++mi)
#pragma unroll
      for (int nj = 0; nj < 4; ++nj) acc[mi][nj] = (floatx4)0.f;
#pragma unroll
    for (int s = 0; s < 2; ++s) {
      bf16x8 af[4], bf[4];
#pragma unroll
      for (int mi = 0; mi < 4; ++mi)
        af[mi] = *(const bf16x8*)&catB[(w * 64 + mi * 16 + mcol) * 72 + s * 32 + qd * 8];
#pragma unroll
      for (int nj = 0; nj < 4; ++nj)
        bf[nj] = *(const bf16x8*)&wB[((nc * 4 + nj) * 16 + mcol) * 72 + s * 32 + qd * 8];
#pragma unroll
      for (int mi = 0; mi < 4; ++mi)
#pragma unroll
        for (int nj = 0; nj < 4; ++nj)
          acc[mi][nj] = __builtin_amdgcn_mfma_f32_16x16x32_bf16(af[mi], bf[nj], acc[mi][nj], 0, 0, 0);
    }
#pragma unroll
    for (int mi = 0; mi < 4; ++mi)
#pragma unroll
      for (int nj = 0; nj < 4; ++nj) {
        const int ch = (nc * 4 + nj) * 16 + mcol;
        const float bb = b2o[ch];
        const int cc = ch >> 2, si = (ch >> 1) & 1, sj = ch & 1;
#pragma unroll
        for (int r = 0; r < 4; ++r) {
          const int tok = w * 64 + mi * 16 + qd * 4 + r;
          const int i = tok >> 4, j = tok & 15;
          h[(size_t)b * 32768 + cc * 1024 + (2 * i + si) * 32 + (2 * j + sj)] =
              (__bf16)(acc[mi][nj][r] + bb);
        }
      }
  }
}

// ---------------- K7: fc1 GEMM bf16 MFMA, full-M blocks --------------------
// grid 512: bn (32 N-tiles of 32) x bk (16 K-chunks of 2048). Each block
// covers all 256 M rows (wave w owns rows w*64..w*64+63) so fc1_w is fetched
// from HBM exactly once (134 MB). A-frags direct from global (L2-resident).
__global__ __launch_bounds__(256) void k7_fc1_gemm(
    const __bf16* __restrict__ A,  // h bf16 [256, 32768]
    const float* __restrict__ Bw,  // fc1_w fp32 [32768, 1024]
    float* __restrict__ part)      // [16][256][1024]
{
  __shared__ __bf16 Bs[32 * 72];
  const int bn = blockIdx.x & 31;
  const int bk = blockIdx.x >> 5;
  const int n0 = bn * 32, k0 = bk * 2048;
  const int tid = threadIdx.x;
  const int n = tid & 31, koct = tid >> 5;
  const int w = tid >> 6, lane = tid & 63;
  const int qd = lane >> 4, mcol = lane & 15;
  floatx4 acc[4][2];
#pragma unroll
  for (int mi = 0; mi < 4; ++mi)
#pragma unroll
    for (int ni = 0; ni < 2; ++ni) acc[mi][ni] = (floatx4)0.f;

  for (int it = 0; it < 32; ++it) {
    const int kk0 = k0 + it * 64;
    float bvals[8];
    const float* brow = Bw + (size_t)(kk0 + koct * 8) * 1024 + n0 + n;
#pragma unroll
    for (int j = 0; j < 8; ++j) bvals[j] = brow[(size_t)j * 1024];
    bf16x8 af[4][2];
#pragma unroll
    for (int mi = 0; mi < 4; ++mi)
#pragma unroll
      for (int s = 0; s < 2; ++s)
        af[mi][s] = *(const bf16x8*)(A + (size_t)(w * 64 + mi * 16 + mcol) * 32768
                                       + kk0 + s * 32 + qd * 8);
    __syncthreads();
    *(bf16x8*)&Bs[n * 72 + koct * 8] = pack8(bvals);
    __syncthreads();
    bf16x8 bf[2][2];
#pragma unroll
    for (int ni = 0; ni < 2; ++ni)
#pragma unroll
      for (int s = 0; s < 2; ++s)
        bf[ni][s] = *(const bf16x8*)&Bs[(ni * 16 + mcol) * 72 + s * 32 + qd * 8];
#pragma unroll
    for (int s = 0; s < 2; ++s)
#pragma unroll
      for (int mi = 0; mi < 4; ++mi)
#pragma unroll
        for (int ni = 0; ni < 2; ++ni)
          acc[mi][ni] = __builtin_amdgcn_mfma_f32_16x16x32_bf16(af[mi][s], bf[ni][s], acc[mi][ni], 0, 0, 0);
  }
  float* P = part + (size_t)bk * 262144;
#pragma unroll
  for (int mi = 0; mi < 4; ++mi)
#pragma unroll
    for (int ni = 0; ni < 2; ++ni) {
      const int col = n0 + ni * 16 + mcol;
#pragma unroll
      for (int r = 0; r < 4; ++r) {
        const int row = w * 64 + mi * 16 + qd * 4 + r;
        P[(size_t)row * 1024 + col] = acc[mi][ni][r];
      }
    }
}

// ---------------- K7c+K8: splitK reduce + bias/relu + fc2 ------------------
__global__ __launch_bounds__(256) void k7c8_fc2(
    const float* __restrict__ part, const float* __restrict__ fc1b,
    const float* __restrict__ w2, const float* __restrict__ b2,
    float* __restrict__ out)
{
  const int b = blockIdx.x, t = threadIdx.x;
  const int col4 = t * 4;
  float4 s = make_float4(0.f, 0.f, 0.f, 0.f);
#pragma unroll
  for (int p = 0; p < 16; ++p) {
    const float4 x4 = *(const float4*)&part[(size_t)p * 262144 + (size_t)b * 1024 + col4];
    s.x += x4.x; s.y += x4.y; s.z += x4.z; s.w += x4.w;
  }
  const float4 bb = *(const float4*)&fc1b[col4];
  float a[4] = {fmaxf(s.x + bb.x, 0.f), fmaxf(s.y + bb.y, 0.f),
                fmaxf(s.z + bb.z, 0.f), fmaxf(s.w + bb.w, 0.f)};
  float acc[10];
#pragma unroll
  for (int o = 0; o < 10; ++o) acc[o] = 0.f;
#pragma unroll
  for (int i = 0; i < 4; ++i) {
    const float* wr = w2 + (size_t)(col4 + i) * 10;
#pragma unroll
    for (int o = 0; o < 10; ++o) acc[o] += a[i] * wr[o];
  }
  __shared__ float red[256][10];
#pragma unroll
  for (int o = 0; o < 10; ++o) red[t][o] = acc[o];
  __syncthreads();
  for (int st = 128; st > 0; st >>= 1) {
    if (t < st) {
#pragma unroll
      for (int o = 0; o < 10; ++o) red[t][o] += red[t + st][o];
    }
    __syncthreads();
  }
  if (t < 10) out[b * 10 + t] = red[0][t] + b2[t];
}

// ---------------------------------------------------------------------------
extern "C" void kernel_launch(void* const* d_in, const int* in_sizes, int n_in,
                              void* d_out, int out_size, void* d_ws, size_t ws_size,
                              hipStream_t stream)
{
  const float* x    = (const float*)d_in[0];
  const float* w1c  = (const float*)d_in[1];
  const float* b1c  = (const float*)d_in[2];
  const float* w1q  = (const float*)d_in[3];
  const float* w1k  = (const float*)d_in[4];
  const float* w1v  = (const float*)d_in[5];
  const float* w1o  = (const float*)d_in[6];
  const float* b1o  = (const float*)d_in[7];
  const float* w2c  = (const float*)d_in[8];
  const float* b2c  = (const float*)d_in[9];
  const float* w2q  = (const float*)d_in[10];
  const float* w2k  = (const float*)d_in[11];
  const float* w2v  = (const float*)d_in[12];
  const float* w2o  = (const float*)d_in[13];
  const float* b2o  = (const float*)d_in[14];
  const float* fc1w = (const float*)d_in[15];
  const float* fc1b = (const float*)d_in[16];
  const float* fc2w = (const float*)d_in[17];
  const float* fc2b = (const float*)d_in[18];
  float* out = (float*)d_out;
  float* ws = (float*)d_ws;

  float* q1   = ws + OQ1;
  float* k1   = ws + OK1;
  float* v1   = ws + OV1;
  float* loc1 = ws + OL1;
  float* agg1 = ws + OA1;
  float* t2   = ws + OT2;
  float* q2   = ws + OQ2;
  float* k2   = ws + OK2;
  float* v2   = ws + OV2;
  float* loc2 = ws + OL2;
  float* agg2 = ws + OA2;
  __bf16* h   = (__bf16*)(ws + OH);
  float* prt  = ws + OPART;

  k1_qkv1<<<16384, 256, 0, stream>>>(x, w1q, w1k, w1v, w1c, b1c, q1, k1, v1, loc1);
  attn_sel<16, 4, 4><<<1024, 256, 0, stream>>>(q1, k1, v1, agg1);
  proj1<<<256, 256, 0, stream>>>(loc1, agg1, w1o, b1o, t2);
  k4_qkv2<<<1024, 256, 0, stream>>>(t2, w2q, w2k, w2v, w2c, b2c, q2, k2, v2, loc2);
  attn_sel<32, 8, 4><<<1024, 256, 0, stream>>>(q2, k2, v2, agg2);
  proj2h<<<256, 256, 0, stream>>>(loc2, agg2, w2o, b2o, h);
  k7_fc1_gemm<<<512, 256, 0, stream>>>(h, fc1w, prt);
  k7c8_fc2<<<256, 256, 0, stream>>>(prt, fc1b, fc2w, fc2b, out);
}